// Round 4
// baseline (1688.349 us; speedup 1.0000x reference)
//
#include <hip/hip_runtime.h>

typedef __bf16 bf16_t;
typedef unsigned short ushort_t;

#define B_ 8
#define T_ 2048
#define C_ 1024
#define HS_ 64

__device__ __forceinline__ float fast_exp2(float x) {
#if __has_builtin(__builtin_amdgcn_exp2f)
  return __builtin_amdgcn_exp2f(x);
#else
  return exp2f(x);
#endif
}

// ---------------------------------------------------------------------------
// Kernel 0: dtype sniffer. flag=1 -> inputs are fp32 (validated in R1->R2:
// bf16 interpretation NaN'd, fp32 interpretation is finite).
// ---------------------------------------------------------------------------
__global__ __launch_bounds__(64) void detect_f32(const ushort_t* __restrict__ x,
                                                 int* __restrict__ flag) {
  int lane = threadIdx.x;
  int cnt = 0;
#pragma unroll
  for (int i = 0; i < 16; ++i) {
    ushort_t u = x[(lane * 16 + i) * 2];
    int e = (u >> 7) & 0xFF;
    cnt += (e >= 96 && e <= 144) ? 1 : 0;
  }
#pragma unroll
  for (int off = 1; off < 64; off <<= 1) cnt += __shfl_xor(cnt, off);
  if (lane == 0) *flag = (cnt < 768) ? 1 : 0;  // 1024 samples, 75% cut
}

// ---------------------------------------------------------------------------
// Kernel 1: naive projections, fp32 accumulate, fp32 outputs.
// One thread per (row, h). grid = (4096, 3): y=0 -> q = x_q@Wq,
// y=1 -> k = x_kv@Wk, y=2 -> v = x_kv@Wv. All row-major [B*T][64].
// ---------------------------------------------------------------------------
__global__ __launch_bounds__(256) void proj_naive(
    const void* __restrict__ xq, const void* __restrict__ xkv,
    const void* __restrict__ Wq, const void* __restrict__ Wk,
    const void* __restrict__ Wv, float* __restrict__ q,
    float* __restrict__ k, float* __restrict__ v,
    const int* __restrict__ flag) {
  const int which = blockIdx.y;
  const void* x = (which == 0) ? xq : xkv;
  const void* W = (which == 0) ? Wq : ((which == 1) ? Wk : Wv);
  float* o = (which == 0) ? q : ((which == 1) ? k : v);
  const int gid = blockIdx.x * 256 + threadIdx.x;
  const int row = gid >> 6, h = gid & 63;
  const bool f32 = (*flag != 0);

  float acc = 0.f;
  if (f32) {
    const float* xr = (const float*)x + (size_t)row * C_;
    const float* Wp = (const float*)W + h;
#pragma unroll 4
    for (int c = 0; c < C_; ++c) acc += xr[c] * Wp[(size_t)c * HS_];
  } else {
    const bf16_t* xr = (const bf16_t*)x + (size_t)row * C_;
    const bf16_t* Wp = (const bf16_t*)W + h;
#pragma unroll 4
    for (int c = 0; c < C_; ++c)
      acc += (float)xr[c] * (float)Wp[(size_t)c * HS_];
  }
  o[(size_t)row * HS_ + h] = acc;
}

// ---------------------------------------------------------------------------
// Kernel 2: naive causal attention, one WAVE per q-row, fp32 throughout,
// online softmax over 64-key chunks. Output is FP32 (reference output dtype
// is float32 per the harness contract; the test's "(bf16,...)" label string
// is hardcoded and carries no dtype information).
// scale = C^-0.5 = 1/32 (reference scales by d_model, not head_size).
// ---------------------------------------------------------------------------
__global__ __launch_bounds__(256) void attn_naive(
    const float* __restrict__ q, const float* __restrict__ k,
    const float* __restrict__ v, float* __restrict__ out) {
  const int w = threadIdx.x >> 6, lane = threadIdx.x & 63;
  const int row = blockIdx.x * 4 + w;        // 0..16383 (= b*T + t)
  const int b = row >> 11, t = row & (T_ - 1);
  const size_t base = (size_t)b * T_ * HS_;
  const float* qr = q + (size_t)row * HS_;   // wave-uniform row
  const float sc = 0.03125f * 1.44269504088896340736f;  // C^-0.5 * log2(e)

  float m_run = -__builtin_inff(), l_run = 0.f, o = 0.f;
  const int nchunk = (t >> 6) + 1;

  for (int c = 0; c < nchunk; ++c) {
    const int s0 = c << 6;
    const int s = s0 + lane;                 // this lane's key row
    const float* kp = k + base + (size_t)s * HS_;
    float dot = 0.f;
#pragma unroll 8
    for (int h = 0; h < HS_; ++h) dot += qr[h] * kp[h];
    const bool valid = (s <= t);
    float score = valid ? dot * sc : -__builtin_inff();

    float mx = score;
#pragma unroll
    for (int off = 1; off < 64; off <<= 1) mx = fmaxf(mx, __shfl_xor(mx, off));
    float mnew = fmaxf(m_run, mx);
    float alpha = fast_exp2(m_run - mnew);   // exp2(-inf)=0 on first chunk
    float p = valid ? fast_exp2(score - mnew) : 0.f;
    float psum = p;
#pragma unroll
    for (int off = 1; off < 64; off <<= 1) psum += __shfl_xor(psum, off);
    l_run = alpha * l_run + psum;
    m_run = mnew;

    o *= alpha;
    const float* vp = v + base + (size_t)s0 * HS_ + lane;  // lane h = lane
#pragma unroll 8
    for (int sp = 0; sp < 64; ++sp) {
      float pj = __shfl(p, sp);              // broadcast key sp's weight
      o += pj * vp[(size_t)sp * HS_];        // coalesced across lanes
    }
  }

  out[(size_t)row * HS_ + lane] = o / l_run;
}

// ---------------------------------------------------------------------------
extern "C" void kernel_launch(void* const* d_in, const int* in_sizes, int n_in,
                              void* d_out, int out_size, void* d_ws,
                              size_t ws_size, hipStream_t stream) {
  (void)in_sizes; (void)n_in; (void)out_size; (void)ws_size;
  const void* xq = d_in[0];
  const void* xkv = d_in[1];
  const void* Wq = d_in[2];
  const void* Wk = d_in[3];
  const void* Wv = d_in[4];
  float* out = (float*)d_out;                // fp32 output per reference dtype

  char* ws = (char*)d_ws;
  float* q = (float*)ws;                     // 4 MB  [B*T][64] fp32
  float* k = (float*)(ws + (4u << 20));      // 4 MB
  float* v = (float*)(ws + (8u << 20));      // 4 MB
  int* flag = (int*)(ws + (12u << 20));

  detect_f32<<<1, 64, 0, stream>>>((const ushort_t*)xq, flag);
  proj_naive<<<dim3(4096, 3), 256, 0, stream>>>(xq, xkv, Wq, Wk, Wv, q, k, v, flag);
  attn_naive<<<dim3(4096), 256, 0, stream>>>(q, k, v, out);
}

// Round 5
// 240.043 us; speedup vs baseline: 7.0335x; 7.0335x over previous
//
#include <hip/hip_runtime.h>

typedef __bf16 bf16_t;
typedef __bf16 bf16x8 __attribute__((ext_vector_type(8)));
typedef float f32x4 __attribute__((ext_vector_type(4)));
typedef unsigned short u16x4 __attribute__((ext_vector_type(4)));

#define B_ 8
#define T_ 2048
#define C_ 1024
#define HS_ 64

#define MFMA __builtin_amdgcn_mfma_f32_16x16x32_bf16

__device__ __forceinline__ float fast_exp2(float x) {
#if __has_builtin(__builtin_amdgcn_exp2f)
  return __builtin_amdgcn_exp2f(x);
#else
  return exp2f(x);
#endif
}

// ---------------------------------------------------------------------------
// Kernel 1: repack W [1024][64] fp32 -> bf16 MFMA B-fragment order.
// Pack index: ((kc*4 + nt)*64 + lane)*8 + j  =  W[kc*32 + quad*8 + j][nt*16 + ln]
// (B-frag layout: lane holds B[k=quad*8+j][n=ln], measured m89/m91.)
// Thread t handles one lane's 8 elements -> one contiguous bf16x8 store.
// ---------------------------------------------------------------------------
__global__ __launch_bounds__(256) void repack_w(
    const float* __restrict__ Wq, const float* __restrict__ Wk,
    const float* __restrict__ Wv, bf16_t* __restrict__ pq,
    bf16_t* __restrict__ pk, bf16_t* __restrict__ pv) {
  const float* W = (blockIdx.y == 0) ? Wq : ((blockIdx.y == 1) ? Wk : Wv);
  bf16_t* P = (blockIdx.y == 0) ? pq : ((blockIdx.y == 1) ? pk : pv);
  int t = blockIdx.x * 256 + threadIdx.x;  // 0..8191
  int lane = t & 63, nt = (t >> 6) & 3, kc = t >> 8;
  int quad = lane >> 4, ln = lane & 15;
  bf16x8 v;
#pragma unroll
  for (int j = 0; j < 8; ++j)
    v[j] = (bf16_t)W[(kc * 32 + quad * 8 + j) * HS_ + nt * 16 + ln];
  *(bf16x8*)(P + (size_t)t * 8) = v;
}

// ---------------------------------------------------------------------------
// Kernel 2: MFMA projections, fp32 x converted to bf16 in the A-load.
// grid (256, 2): y=0 -> q = x_q@Wq; y=1 -> k = x_kv@Wk AND v = x_kv@Wv
// (shared A fragments). q,k row-major [B*T][64] bf16; v transposed
// [B][64][T] bf16 (keys contiguous -> PV B-frags are 16B loads; C-layout rows
// quad*4+r are 4 consecutive keys -> packed 8B stores).
// ---------------------------------------------------------------------------
__global__ __launch_bounds__(256) void proj_mfma(
    const float* __restrict__ xq, const float* __restrict__ xkv,
    const bf16_t* __restrict__ pq, const bf16_t* __restrict__ pk,
    const bf16_t* __restrict__ pv, bf16_t* __restrict__ q,
    bf16_t* __restrict__ k, bf16_t* __restrict__ vT) {
  const int rt = blockIdx.x;
  const bool is_kv = (blockIdx.y != 0);
  const int w = threadIdx.x >> 6, lane = threadIdx.x & 63;
  const int quad = lane >> 4, ln = lane & 15;
  const int m0 = rt * 64 + w * 16;
  const float* x = is_kv ? xkv : xq;
  const bf16_t* p0 = is_kv ? pk : pq;

  f32x4 acc0[4], acc1[4];
#pragma unroll
  for (int nt = 0; nt < 4; ++nt) {
    acc0[nt] = (f32x4){0.f, 0.f, 0.f, 0.f};
    acc1[nt] = (f32x4){0.f, 0.f, 0.f, 0.f};
  }

  for (int kc = 0; kc < 32; ++kc) {
    const float* xf = x + (size_t)(m0 + ln) * C_ + kc * 32 + quad * 8;
    f32x4 lo = *(const f32x4*)xf;
    f32x4 hi = *(const f32x4*)(xf + 4);
    bf16x8 a;
#pragma unroll
    for (int j = 0; j < 4; ++j) {
      a[j] = (bf16_t)lo[j];
      a[4 + j] = (bf16_t)hi[j];
    }
#pragma unroll
    for (int nt = 0; nt < 4; ++nt) {
      bf16x8 b = *(const bf16x8*)(p0 + ((size_t)(kc * 4 + nt) * 64 + lane) * 8);
      acc0[nt] = MFMA(a, b, acc0[nt], 0, 0, 0);
    }
    if (is_kv) {
#pragma unroll
      for (int nt = 0; nt < 4; ++nt) {
        bf16x8 b = *(const bf16x8*)(pv + ((size_t)(kc * 4 + nt) * 64 + lane) * 8);
        acc1[nt] = MFMA(a, b, acc1[nt], 0, 0, 0);
      }
    }
  }

  if (!is_kv) {
#pragma unroll
    for (int nt = 0; nt < 4; ++nt)
#pragma unroll
      for (int r = 0; r < 4; ++r)
        q[(size_t)(m0 + quad * 4 + r) * HS_ + nt * 16 + ln] = (bf16_t)acc0[nt][r];
  } else {
#pragma unroll
    for (int nt = 0; nt < 4; ++nt)
#pragma unroll
      for (int r = 0; r < 4; ++r)
        k[(size_t)(m0 + quad * 4 + r) * HS_ + nt * 16 + ln] = (bf16_t)acc0[nt][r];
    const int bb = m0 >> 11, t0 = m0 & (T_ - 1);
#pragma unroll
    for (int nt = 0; nt < 4; ++nt) {
      u16x4 pk4;
#pragma unroll
      for (int r = 0; r < 4; ++r) {
        bf16_t h = (bf16_t)acc1[nt][r];
        pk4[r] = *(unsigned short*)&h;
      }
      *(u16x4*)((unsigned short*)vT + ((size_t)(bb * HS_ + nt * 16 + ln)) * T_ +
                t0 + quad * 4) = pk4;
    }
  }
}

// ---------------------------------------------------------------------------
// Kernel 3: causal flash attention, KV-split x4.
// grid = B * 128 blocks; block = one 16-row q-group, 4 waves. Wave w handles
// k-tiles {w, w+4, ...} <= td. Scores bounded (|s| <~ 1.3) => fixed softmax
// max (m=0): p = exp2(s*scale*log2e), l deferred to a single end reduction,
// partials across waves combine by ADDITION through LDS.
// P round-trips LDS (C-layout -> A-layout), row stride 80 elems = 160 B
// (16B-aligned for ds_read_b128). scale = C^-0.5 = 1/32.
// ---------------------------------------------------------------------------
__global__ __launch_bounds__(256) void attn_mfma(
    const bf16_t* __restrict__ q, const bf16_t* __restrict__ k,
    const bf16_t* __restrict__ vT, float* __restrict__ out) {
  __shared__ bf16_t p_lds[4][16][80];   // 10 KB: per-wave P transpose
  __shared__ float o_buf[3][16][64];    // 12 KB: waves 1..3 partial O
  __shared__ float l_buf[4][16][16];    //  4 KB: per-lane l partials

  const int b = blockIdx.x >> 7;
  const int gq = blockIdx.x & 127;      // 16-row q-group within batch
  const int w = threadIdx.x >> 6, lane = threadIdx.x & 63;
  const int quad = lane >> 4, ln = lane & 15;
  const int qr0 = gq * 16;
  const size_t bt = (size_t)b * T_;
  const int td = gq >> 2;               // diagonal 64-key tile index

  bf16x8 aq[2];
#pragma unroll
  for (int hc = 0; hc < 2; ++hc)
    aq[hc] = *(const bf16x8*)(q + (bt + qr0 + ln) * HS_ + hc * 32 + quad * 8);

  f32x4 o_acc[4];
  float l_part[4] = {0.f, 0.f, 0.f, 0.f};
#pragma unroll
  for (int nt = 0; nt < 4; ++nt) o_acc[nt] = (f32x4){0.f, 0.f, 0.f, 0.f};
  const float scl = 0.03125f * 1.44269504088896340736f;  // C^-0.5 * log2(e)

  for (int t = w; t <= td; t += 4) {
    const int kr0 = t * 64;

    // ---- S = Q K^T (16 q-rows x 64 keys) ----
    f32x4 s[4];
#pragma unroll
    for (int nt = 0; nt < 4; ++nt) s[nt] = (f32x4){0.f, 0.f, 0.f, 0.f};
#pragma unroll
    for (int hc = 0; hc < 2; ++hc)
#pragma unroll
      for (int nt = 0; nt < 4; ++nt) {
        bf16x8 bk = *(const bf16x8*)(k + (bt + kr0 + nt * 16 + ln) * HS_ +
                                     hc * 32 + quad * 8);
        s[nt] = MFMA(aq[hc], bk, s[nt], 0, 0, 0);
      }

    // ---- p = exp(s/32), mask diagonal tile, accumulate l, stage P ----
    const bool diag = (t == td);
#pragma unroll
    for (int nt = 0; nt < 4; ++nt)
#pragma unroll
      for (int r = 0; r < 4; ++r) {
        float e = fast_exp2(s[nt][r] * scl);
        if (diag && (kr0 + nt * 16 + ln > qr0 + quad * 4 + r)) e = 0.f;
        l_part[r] += e;
        p_lds[w][quad * 4 + r][nt * 16 + ln] = (bf16_t)e;
      }

    // ---- O += P V (per-wave LDS slice; same-wave DS ordering) ----
#pragma unroll
    for (int kc = 0; kc < 2; ++kc) {
      bf16x8 ap = *(const bf16x8*)&p_lds[w][ln][kc * 32 + quad * 8];
#pragma unroll
      for (int nt = 0; nt < 4; ++nt) {
        bf16x8 bv = *(const bf16x8*)(vT + ((size_t)(b * HS_ + nt * 16 + ln)) * T_ +
                                     kr0 + kc * 32 + quad * 8);
        o_acc[nt] = MFMA(ap, bv, o_acc[nt], 0, 0, 0);
      }
    }
  }

  // ---- combine the 4 KV-split partials (pure addition, fixed m) ----
  if (w != 0) {
#pragma unroll
    for (int nt = 0; nt < 4; ++nt)
#pragma unroll
      for (int r = 0; r < 4; ++r)
        o_buf[w - 1][quad * 4 + r][nt * 16 + ln] = o_acc[nt][r];
  }
#pragma unroll
  for (int r = 0; r < 4; ++r) l_buf[w][quad * 4 + r][ln] = l_part[r];
  __syncthreads();

  if (w == 0) {
#pragma unroll
    for (int ww = 0; ww < 3; ++ww)
#pragma unroll
      for (int nt = 0; nt < 4; ++nt)
#pragma unroll
        for (int r = 0; r < 4; ++r)
          o_acc[nt][r] += o_buf[ww][quad * 4 + r][nt * 16 + ln];
    float l_row[4];
#pragma unroll
    for (int r = 0; r < 4; ++r) {
      float v = l_buf[0][quad * 4 + r][ln] + l_buf[1][quad * 4 + r][ln] +
                l_buf[2][quad * 4 + r][ln] + l_buf[3][quad * 4 + r][ln];
#pragma unroll
      for (int off = 1; off < 16; off <<= 1) v += __shfl_xor(v, off);
      l_row[r] = v;
    }
#pragma unroll
    for (int nt = 0; nt < 4; ++nt)
#pragma unroll
      for (int r = 0; r < 4; ++r)
        out[(bt + qr0 + quad * 4 + r) * HS_ + nt * 16 + ln] =
            o_acc[nt][r] / l_row[r];
  }
}

// ---------------------------------------------------------------------------
extern "C" void kernel_launch(void* const* d_in, const int* in_sizes, int n_in,
                              void* d_out, int out_size, void* d_ws,
                              size_t ws_size, hipStream_t stream) {
  (void)in_sizes; (void)n_in; (void)out_size; (void)ws_size;
  const float* xq = (const float*)d_in[0];   // fp32 inputs: proven in R1->R4
  const float* xkv = (const float*)d_in[1];
  const float* Wq = (const float*)d_in[2];
  const float* Wk = (const float*)d_in[3];
  const float* Wv = (const float*)d_in[4];
  float* out = (float*)d_out;                // fp32 output: proven in R4

  char* ws = (char*)d_ws;
  bf16_t* q = (bf16_t*)ws;                              // 2 MB  [B*T][64]
  bf16_t* kk = (bf16_t*)(ws + (2u << 20));              // 2 MB  [B*T][64]
  bf16_t* vT = (bf16_t*)(ws + (4u << 20));              // 2 MB  [B][64][T]
  bf16_t* pq = (bf16_t*)(ws + (6u << 20));              // 128 KB packed W
  bf16_t* pk = (bf16_t*)(ws + (6u << 20) + (128u << 10));
  bf16_t* pv = (bf16_t*)(ws + (6u << 20) + (256u << 10));

  repack_w<<<dim3(32, 3), 256, 0, stream>>>(Wq, Wk, Wv, pq, pk, pv);
  proj_mfma<<<dim3(256, 2), 256, 0, stream>>>(xq, xkv, pq, pk, pv, q, kk, vT);
  attn_mfma<<<dim3(1024), 256, 0, stream>>>(q, kk, vT, out);
}

// Round 6
// 221.359 us; speedup vs baseline: 7.6272x; 1.0844x over previous
//
#include <hip/hip_runtime.h>

typedef __bf16 bf16_t;
typedef __bf16 bf16x8 __attribute__((ext_vector_type(8)));
typedef float f32x4 __attribute__((ext_vector_type(4)));
typedef unsigned short u16x4 __attribute__((ext_vector_type(4)));

#define B_ 8
#define T_ 2048
#define C_ 1024
#define HS_ 64

#define MFMA __builtin_amdgcn_mfma_f32_16x16x32_bf16

__device__ __forceinline__ float fast_exp2(float x) {
#if __has_builtin(__builtin_amdgcn_exp2f)
  return __builtin_amdgcn_exp2f(x);
#else
  return exp2f(x);
#endif
}

// ---------------------------------------------------------------------------
// Kernel 1: repack W [1024][64] fp32 -> bf16 MFMA B-fragment order.
// Pack index: ((kc*4 + nt)*64 + lane)*8 + j  =  W[kc*32 + quad*8 + j][nt*16 + ln]
// ---------------------------------------------------------------------------
__global__ __launch_bounds__(256) void repack_w(
    const float* __restrict__ Wq, const float* __restrict__ Wk,
    const float* __restrict__ Wv, bf16_t* __restrict__ pq,
    bf16_t* __restrict__ pk, bf16_t* __restrict__ pv) {
  const float* W = (blockIdx.y == 0) ? Wq : ((blockIdx.y == 1) ? Wk : Wv);
  bf16_t* P = (blockIdx.y == 0) ? pq : ((blockIdx.y == 1) ? pk : pv);
  int t = blockIdx.x * 256 + threadIdx.x;  // 0..8191
  int lane = t & 63, nt = (t >> 6) & 3, kc = t >> 8;
  int quad = lane >> 4, ln = lane & 15;
  bf16x8 v;
#pragma unroll
  for (int j = 0; j < 8; ++j)
    v[j] = (bf16_t)W[(kc * 32 + quad * 8 + j) * HS_ + nt * 16 + ln];
  *(bf16x8*)(P + (size_t)t * 8) = v;
}

// ---------------------------------------------------------------------------
// Kernel 2: MFMA projections, K-split x2 for occupancy (R5: 2 waves/SIMD was
// the bottleneck — 17% occupancy, all pipes <14%).
// Block = 512 thr = 8 waves. Wave (wr, kh): rows rt*64+wr*16, K-half kh.
// Partials merged via LDS (stride 68 floats -> 2-way banks = free), kh=0
// stores. y=0: q = x_q@Wq. y=1: k = x_kv@Wk AND v = x_kv@Wv (shared A).
// q,k row-major [B*T][64] bf16; v transposed [B][64][T] bf16.
// ---------------------------------------------------------------------------
__global__ __launch_bounds__(512) void proj_mfma(
    const float* __restrict__ xq, const float* __restrict__ xkv,
    const bf16_t* __restrict__ pq, const bf16_t* __restrict__ pk,
    const bf16_t* __restrict__ pv, bf16_t* __restrict__ q,
    bf16_t* __restrict__ k, bf16_t* __restrict__ vT) {
  __shared__ float r0[4][16][68];  // 17 KB: kh=1 partial (q or k)
  __shared__ float r1[4][16][68];  // 17 KB: kh=1 partial (v)

  const int rt = blockIdx.x;
  const bool is_kv = (blockIdx.y != 0);
  const int wv = threadIdx.x >> 6, lane = threadIdx.x & 63;
  const int wr = wv & 3, kh = wv >> 2;
  const int quad = lane >> 4, ln = lane & 15;
  const int m0 = rt * 64 + wr * 16;
  const float* x = is_kv ? xkv : xq;
  const bf16_t* p0 = is_kv ? pk : pq;

  f32x4 acc0[4], acc1[4];
#pragma unroll
  for (int nt = 0; nt < 4; ++nt) {
    acc0[nt] = (f32x4){0.f, 0.f, 0.f, 0.f};
    acc1[nt] = (f32x4){0.f, 0.f, 0.f, 0.f};
  }

  for (int kc = kh * 16; kc < kh * 16 + 16; ++kc) {
    const float* xf = x + (size_t)(m0 + ln) * C_ + kc * 32 + quad * 8;
    f32x4 lo = *(const f32x4*)xf;
    f32x4 hi = *(const f32x4*)(xf + 4);
    bf16x8 a;
#pragma unroll
    for (int j = 0; j < 4; ++j) {
      a[j] = (bf16_t)lo[j];
      a[4 + j] = (bf16_t)hi[j];
    }
#pragma unroll
    for (int nt = 0; nt < 4; ++nt) {
      bf16x8 b = *(const bf16x8*)(p0 + ((size_t)(kc * 4 + nt) * 64 + lane) * 8);
      acc0[nt] = MFMA(a, b, acc0[nt], 0, 0, 0);
    }
    if (is_kv) {
#pragma unroll
      for (int nt = 0; nt < 4; ++nt) {
        bf16x8 b = *(const bf16x8*)(pv + ((size_t)(kc * 4 + nt) * 64 + lane) * 8);
        acc1[nt] = MFMA(a, b, acc1[nt], 0, 0, 0);
      }
    }
  }

  if (kh == 1) {
#pragma unroll
    for (int nt = 0; nt < 4; ++nt)
#pragma unroll
      for (int r = 0; r < 4; ++r) {
        r0[wr][quad * 4 + r][nt * 16 + ln] = acc0[nt][r];
        if (is_kv) r1[wr][quad * 4 + r][nt * 16 + ln] = acc1[nt][r];
      }
  }
  __syncthreads();
  if (kh != 0) return;

#pragma unroll
  for (int nt = 0; nt < 4; ++nt)
#pragma unroll
    for (int r = 0; r < 4; ++r) {
      acc0[nt][r] += r0[wr][quad * 4 + r][nt * 16 + ln];
      if (is_kv) acc1[nt][r] += r1[wr][quad * 4 + r][nt * 16 + ln];
    }

  if (!is_kv) {
#pragma unroll
    for (int nt = 0; nt < 4; ++nt)
#pragma unroll
      for (int r = 0; r < 4; ++r)
        q[(size_t)(m0 + quad * 4 + r) * HS_ + nt * 16 + ln] = (bf16_t)acc0[nt][r];
  } else {
#pragma unroll
    for (int nt = 0; nt < 4; ++nt)
#pragma unroll
      for (int r = 0; r < 4; ++r)
        k[(size_t)(m0 + quad * 4 + r) * HS_ + nt * 16 + ln] = (bf16_t)acc0[nt][r];
    const int bb = m0 >> 11, t0 = m0 & (T_ - 1);
#pragma unroll
    for (int nt = 0; nt < 4; ++nt) {
      u16x4 pk4;
#pragma unroll
      for (int r = 0; r < 4; ++r) {
        bf16_t h = (bf16_t)acc1[nt][r];
        pk4[r] = *(unsigned short*)&h;
      }
      *(u16x4*)((unsigned short*)vT + ((size_t)(bb * HS_ + nt * 16 + ln)) * T_ +
                t0 + quad * 4) = pk4;
    }
  }
}

// ---------------------------------------------------------------------------
// Kernel 3: causal flash attention, KV-split x8 (was x4; longest serial
// chain drops 8 -> 4 tiles, waves 4096 -> 8192 = device-full).
// grid = B*128; block = one 16-row q-group, 8 waves. Wave w handles k-tiles
// {w, w+8, ...} <= td. Fixed softmax max (|s| <~ 1.5): p = exp2(s*scl),
// l deferred; partials combine by ADDITION through LDS. P round-trips LDS
// C-layout -> A-layout (stride 80 elems = 160 B, 16B-aligned).
// scale = C^-0.5 = 1/32 (reference uses d_model, not head_size).
// ---------------------------------------------------------------------------
__global__ __launch_bounds__(512) void attn_mfma(
    const bf16_t* __restrict__ q, const bf16_t* __restrict__ k,
    const bf16_t* __restrict__ vT, float* __restrict__ out) {
  __shared__ bf16_t p_lds[8][16][80];   // 20 KB: per-wave P transpose
  __shared__ float o_buf[7][16][68];    // 30 KB: waves 1..7 partial O
  __shared__ float l_buf[8][16][16];    //  8 KB: per-lane l partials

  const int b = blockIdx.x >> 7;
  const int gq = blockIdx.x & 127;      // 16-row q-group within batch
  const int w = threadIdx.x >> 6, lane = threadIdx.x & 63;
  const int quad = lane >> 4, ln = lane & 15;
  const int qr0 = gq * 16;
  const size_t bt = (size_t)b * T_;
  const int td = gq >> 2;               // diagonal 64-key tile index

  bf16x8 aq[2];
#pragma unroll
  for (int hc = 0; hc < 2; ++hc)
    aq[hc] = *(const bf16x8*)(q + (bt + qr0 + ln) * HS_ + hc * 32 + quad * 8);

  f32x4 o_acc[4];
  float l_part[4] = {0.f, 0.f, 0.f, 0.f};
#pragma unroll
  for (int nt = 0; nt < 4; ++nt) o_acc[nt] = (f32x4){0.f, 0.f, 0.f, 0.f};
  const float scl = 0.03125f * 1.44269504088896340736f;  // C^-0.5 * log2(e)

  for (int t = w; t <= td; t += 8) {
    const int kr0 = t * 64;

    // ---- S = Q K^T (16 q-rows x 64 keys) ----
    f32x4 s[4];
#pragma unroll
    for (int nt = 0; nt < 4; ++nt) s[nt] = (f32x4){0.f, 0.f, 0.f, 0.f};
#pragma unroll
    for (int hc = 0; hc < 2; ++hc)
#pragma unroll
      for (int nt = 0; nt < 4; ++nt) {
        bf16x8 bk = *(const bf16x8*)(k + (bt + kr0 + nt * 16 + ln) * HS_ +
                                     hc * 32 + quad * 8);
        s[nt] = MFMA(aq[hc], bk, s[nt], 0, 0, 0);
      }

    // ---- p = exp(s/32), mask diagonal tile, accumulate l, stage P ----
    const bool diag = (t == td);
#pragma unroll
    for (int nt = 0; nt < 4; ++nt)
#pragma unroll
      for (int r = 0; r < 4; ++r) {
        float e = fast_exp2(s[nt][r] * scl);
        if (diag && (kr0 + nt * 16 + ln > qr0 + quad * 4 + r)) e = 0.f;
        l_part[r] += e;
        p_lds[w][quad * 4 + r][nt * 16 + ln] = (bf16_t)e;
      }

    // ---- O += P V (per-wave LDS slice; same-wave DS ordering) ----
#pragma unroll
    for (int kc = 0; kc < 2; ++kc) {
      bf16x8 ap = *(const bf16x8*)&p_lds[w][ln][kc * 32 + quad * 8];
#pragma unroll
      for (int nt = 0; nt < 4; ++nt) {
        bf16x8 bv = *(const bf16x8*)(vT + ((size_t)(b * HS_ + nt * 16 + ln)) * T_ +
                                     kr0 + kc * 32 + quad * 8);
        o_acc[nt] = MFMA(ap, bv, o_acc[nt], 0, 0, 0);
      }
    }
  }

  // ---- combine the 8 KV-split partials (pure addition, fixed m) ----
  if (w != 0) {
#pragma unroll
    for (int nt = 0; nt < 4; ++nt)
#pragma unroll
      for (int r = 0; r < 4; ++r)
        o_buf[w - 1][quad * 4 + r][nt * 16 + ln] = o_acc[nt][r];
  }
#pragma unroll
  for (int r = 0; r < 4; ++r) l_buf[w][quad * 4 + r][ln] = l_part[r];
  __syncthreads();

  if (w == 0) {
#pragma unroll
    for (int ww = 0; ww < 7; ++ww)
#pragma unroll
      for (int nt = 0; nt < 4; ++nt)
#pragma unroll
        for (int r = 0; r < 4; ++r)
          o_acc[nt][r] += o_buf[ww][quad * 4 + r][nt * 16 + ln];
    float l_row[4];
#pragma unroll
    for (int r = 0; r < 4; ++r) {
      float v = 0.f;
#pragma unroll
      for (int ww = 0; ww < 8; ++ww) v += l_buf[ww][quad * 4 + r][ln];
#pragma unroll
      for (int off = 1; off < 16; off <<= 1) v += __shfl_xor(v, off);
      l_row[r] = v;
    }
#pragma unroll
    for (int nt = 0; nt < 4; ++nt)
#pragma unroll
      for (int r = 0; r < 4; ++r)
        out[(bt + qr0 + quad * 4 + r) * HS_ + nt * 16 + ln] =
            o_acc[nt][r] / l_row[r];
  }
}

// ---------------------------------------------------------------------------
extern "C" void kernel_launch(void* const* d_in, const int* in_sizes, int n_in,
                              void* d_out, int out_size, void* d_ws,
                              size_t ws_size, hipStream_t stream) {
  (void)in_sizes; (void)n_in; (void)out_size; (void)ws_size;
  const float* xq = (const float*)d_in[0];   // fp32 in / fp32 out: proven R4
  const float* xkv = (const float*)d_in[1];
  const float* Wq = (const float*)d_in[2];
  const float* Wk = (const float*)d_in[3];
  const float* Wv = (const float*)d_in[4];
  float* out = (float*)d_out;

  char* ws = (char*)d_ws;
  bf16_t* q = (bf16_t*)ws;                              // 2 MB  [B*T][64]
  bf16_t* kk = (bf16_t*)(ws + (2u << 20));              // 2 MB  [B*T][64]
  bf16_t* vT = (bf16_t*)(ws + (4u << 20));              // 2 MB  [B][64][T]
  bf16_t* pq = (bf16_t*)(ws + (6u << 20));              // 128 KB packed W
  bf16_t* pk = (bf16_t*)(ws + (6u << 20) + (128u << 10));
  bf16_t* pv = (bf16_t*)(ws + (6u << 20) + (256u << 10));

  repack_w<<<dim3(32, 3), 256, 0, stream>>>(Wq, Wk, Wv, pq, pk, pv);
  proj_mfma<<<dim3(256, 2), 512, 0, stream>>>(xq, xkv, pq, pk, pv, q, kk, vT);
  attn_mfma<<<dim3(1024), 512, 0, stream>>>(q, kk, vT, out);
}

// Round 7
// 219.704 us; speedup vs baseline: 7.6847x; 1.0075x over previous
//
#include <hip/hip_runtime.h>

typedef __bf16 bf16_t;
typedef __bf16 bf16x8 __attribute__((ext_vector_type(8)));
typedef float f32x4 __attribute__((ext_vector_type(4)));
typedef unsigned short u16x4 __attribute__((ext_vector_type(4)));

#define B_ 8
#define T_ 2048
#define C_ 1024
#define HS_ 64

#define MFMA __builtin_amdgcn_mfma_f32_16x16x32_bf16

__device__ __forceinline__ float fast_exp2(float x) {
#if __has_builtin(__builtin_amdgcn_exp2f)
  return __builtin_amdgcn_exp2f(x);
#else
  return exp2f(x);
#endif
}

// ---------------------------------------------------------------------------
// Kernel 1: repack W [1024][64] fp32 -> bf16 MFMA B-fragment order.
// Pack index: ((kc*4 + nt)*64 + lane)*8 + j  =  W[kc*32 + quad*8 + j][nt*16 + ln]
// ---------------------------------------------------------------------------
__global__ __launch_bounds__(256) void repack_w(
    const float* __restrict__ Wq, const float* __restrict__ Wk,
    const float* __restrict__ Wv, bf16_t* __restrict__ pq,
    bf16_t* __restrict__ pk, bf16_t* __restrict__ pv) {
  const float* W = (blockIdx.y == 0) ? Wq : ((blockIdx.y == 1) ? Wk : Wv);
  bf16_t* P = (blockIdx.y == 0) ? pq : ((blockIdx.y == 1) ? pk : pv);
  int t = blockIdx.x * 256 + threadIdx.x;  // 0..8191
  int lane = t & 63, nt = (t >> 6) & 3, kc = t >> 8;
  int quad = lane >> 4, ln = lane & 15;
  bf16x8 v;
#pragma unroll
  for (int j = 0; j < 8; ++j)
    v[j] = (bf16_t)W[(kc * 32 + quad * 8 + j) * HS_ + nt * 16 + ln];
  *(bf16x8*)(P + (size_t)t * 8) = v;
}

// ---------------------------------------------------------------------------
// Kernel 2: MFMA projections, K-split x2, K-loop unrolled x4 with hoisted
// loads (R6 diagnosis: only 2 HBM loads in flight per wave -> 1270 GB/s;
// 8 in flight raises the duty cycle). Partial merge via LDS, stride 66
// floats (272-dword quad stride was 4-way bank conflicted; 264 ≡ 8 mod 32
// -> 2-way = free). y=0: q = x_q@Wq; y=1: k = x_kv@Wk AND v = x_kv@Wv.
// q,k row-major [B*T][64] bf16; v transposed [B][64][T] bf16.
// ---------------------------------------------------------------------------
__global__ __launch_bounds__(512) void proj_mfma(
    const float* __restrict__ xq, const float* __restrict__ xkv,
    const bf16_t* __restrict__ pq, const bf16_t* __restrict__ pk,
    const bf16_t* __restrict__ pv, bf16_t* __restrict__ q,
    bf16_t* __restrict__ k, bf16_t* __restrict__ vT) {
  __shared__ float r0[4][16][66];  // kh=1 partial (q or k)
  __shared__ float r1[4][16][66];  // kh=1 partial (v)

  const int rt = blockIdx.x;
  const bool is_kv = (blockIdx.y != 0);
  const int wv = threadIdx.x >> 6, lane = threadIdx.x & 63;
  const int wr = wv & 3, kh = wv >> 2;
  const int quad = lane >> 4, ln = lane & 15;
  const int m0 = rt * 64 + wr * 16;
  const float* x = is_kv ? xkv : xq;
  const bf16_t* p0 = is_kv ? pk : pq;

  f32x4 acc0[4], acc1[4];
#pragma unroll
  for (int nt = 0; nt < 4; ++nt) {
    acc0[nt] = (f32x4){0.f, 0.f, 0.f, 0.f};
    acc1[nt] = (f32x4){0.f, 0.f, 0.f, 0.f};
  }

  for (int kc = kh * 16; kc < kh * 16 + 16; kc += 4) {
    f32x4 lo[4], hi[4];
#pragma unroll
    for (int u = 0; u < 4; ++u) {
      const float* xf = x + (size_t)(m0 + ln) * C_ + (kc + u) * 32 + quad * 8;
      lo[u] = *(const f32x4*)xf;
      hi[u] = *(const f32x4*)(xf + 4);
    }
#pragma unroll
    for (int u = 0; u < 4; ++u) {
      bf16x8 a;
#pragma unroll
      for (int j = 0; j < 4; ++j) {
        a[j] = (bf16_t)lo[u][j];
        a[4 + j] = (bf16_t)hi[u][j];
      }
#pragma unroll
      for (int nt = 0; nt < 4; ++nt) {
        bf16x8 b =
            *(const bf16x8*)(p0 + ((size_t)((kc + u) * 4 + nt) * 64 + lane) * 8);
        acc0[nt] = MFMA(a, b, acc0[nt], 0, 0, 0);
      }
      if (is_kv) {
#pragma unroll
        for (int nt = 0; nt < 4; ++nt) {
          bf16x8 b =
              *(const bf16x8*)(pv + ((size_t)((kc + u) * 4 + nt) * 64 + lane) * 8);
          acc1[nt] = MFMA(a, b, acc1[nt], 0, 0, 0);
        }
      }
    }
  }

  if (kh == 1) {
#pragma unroll
    for (int nt = 0; nt < 4; ++nt)
#pragma unroll
      for (int r = 0; r < 4; ++r) {
        r0[wr][quad * 4 + r][nt * 16 + ln] = acc0[nt][r];
        if (is_kv) r1[wr][quad * 4 + r][nt * 16 + ln] = acc1[nt][r];
      }
  }
  __syncthreads();
  if (kh != 0) return;

#pragma unroll
  for (int nt = 0; nt < 4; ++nt)
#pragma unroll
    for (int r = 0; r < 4; ++r) {
      acc0[nt][r] += r0[wr][quad * 4 + r][nt * 16 + ln];
      if (is_kv) acc1[nt][r] += r1[wr][quad * 4 + r][nt * 16 + ln];
    }

  if (!is_kv) {
#pragma unroll
    for (int nt = 0; nt < 4; ++nt)
#pragma unroll
      for (int r = 0; r < 4; ++r)
        q[(size_t)(m0 + quad * 4 + r) * HS_ + nt * 16 + ln] = (bf16_t)acc0[nt][r];
  } else {
#pragma unroll
    for (int nt = 0; nt < 4; ++nt)
#pragma unroll
      for (int r = 0; r < 4; ++r)
        k[(size_t)(m0 + quad * 4 + r) * HS_ + nt * 16 + ln] = (bf16_t)acc0[nt][r];
    const int bb = m0 >> 11, t0 = m0 & (T_ - 1);
#pragma unroll
    for (int nt = 0; nt < 4; ++nt) {
      u16x4 pk4;
#pragma unroll
      for (int r = 0; r < 4; ++r) {
        bf16_t h = (bf16_t)acc1[nt][r];
        pk4[r] = *(unsigned short*)&h;
      }
      *(u16x4*)((unsigned short*)vT + ((size_t)(bb * HS_ + nt * 16 + ln)) * T_ +
                t0 + quad * 4) = pk4;
    }
  }
}

// ---------------------------------------------------------------------------
// Kernel 3: causal flash attention, KV-split x8, parallel epilogue.
// grid = B*128; block = one 16-row q-group, 8 waves; wave w: k-tiles
// {w, w+8, ...} <= td. Fixed softmax max (|s| <~ 1.5): p = exp2(s*scl),
// l deferred; partials combine by ADDITION. All 8 waves dump partials to
// LDS; wave w then reduces rows {w, w+8} (coalesced 256B output stores).
// o_buf stride 66 / l_buf stride 17: bank-conflict-free write patterns.
// P transpose stride 80 elems = 160 B (16B-aligned for ds_read_b128).
// scale = C^-0.5 = 1/32 (reference uses d_model, not head_size).
// ---------------------------------------------------------------------------
__global__ __launch_bounds__(512) void attn_mfma(
    const bf16_t* __restrict__ q, const bf16_t* __restrict__ k,
    const bf16_t* __restrict__ vT, float* __restrict__ out) {
  __shared__ bf16_t p_lds[8][16][80];   // 20 KB: per-wave P transpose
  __shared__ float o_buf[8][16][66];    // 33 KB: all 8 waves' partial O
  __shared__ float l_buf[8][16][17];    //  8.7 KB: per-lane l partials

  const int b = blockIdx.x >> 7;
  const int gq = blockIdx.x & 127;      // 16-row q-group within batch
  const int w = threadIdx.x >> 6, lane = threadIdx.x & 63;
  const int quad = lane >> 4, ln = lane & 15;
  const int qr0 = gq * 16;
  const size_t bt = (size_t)b * T_;
  const int td = gq >> 2;               // diagonal 64-key tile index

  bf16x8 aq[2];
#pragma unroll
  for (int hc = 0; hc < 2; ++hc)
    aq[hc] = *(const bf16x8*)(q + (bt + qr0 + ln) * HS_ + hc * 32 + quad * 8);

  f32x4 o_acc[4];
  float l_part[4] = {0.f, 0.f, 0.f, 0.f};
#pragma unroll
  for (int nt = 0; nt < 4; ++nt) o_acc[nt] = (f32x4){0.f, 0.f, 0.f, 0.f};
  const float scl = 0.03125f * 1.44269504088896340736f;  // C^-0.5 * log2(e)

  for (int t = w; t <= td; t += 8) {
    const int kr0 = t * 64;

    // ---- S = Q K^T (16 q-rows x 64 keys) ----
    f32x4 s[4];
#pragma unroll
    for (int nt = 0; nt < 4; ++nt) s[nt] = (f32x4){0.f, 0.f, 0.f, 0.f};
#pragma unroll
    for (int hc = 0; hc < 2; ++hc)
#pragma unroll
      for (int nt = 0; nt < 4; ++nt) {
        bf16x8 bk = *(const bf16x8*)(k + (bt + kr0 + nt * 16 + ln) * HS_ +
                                     hc * 32 + quad * 8);
        s[nt] = MFMA(aq[hc], bk, s[nt], 0, 0, 0);
      }

    // ---- p = exp(s/32), mask diagonal tile, accumulate l, stage P ----
    const bool diag = (t == td);
#pragma unroll
    for (int nt = 0; nt < 4; ++nt)
#pragma unroll
      for (int r = 0; r < 4; ++r) {
        float e = fast_exp2(s[nt][r] * scl);
        if (diag && (kr0 + nt * 16 + ln > qr0 + quad * 4 + r)) e = 0.f;
        l_part[r] += e;
        p_lds[w][quad * 4 + r][nt * 16 + ln] = (bf16_t)e;
      }

    // ---- O += P V (per-wave LDS slice; same-wave DS ordering) ----
#pragma unroll
    for (int kc = 0; kc < 2; ++kc) {
      bf16x8 ap = *(const bf16x8*)&p_lds[w][ln][kc * 32 + quad * 8];
#pragma unroll
      for (int nt = 0; nt < 4; ++nt) {
        bf16x8 bv = *(const bf16x8*)(vT + ((size_t)(b * HS_ + nt * 16 + ln)) * T_ +
                                     kr0 + kc * 32 + quad * 8);
        o_acc[nt] = MFMA(ap, bv, o_acc[nt], 0, 0, 0);
      }
    }
  }

  // ---- all waves dump partials; combine split across waves ----
#pragma unroll
  for (int nt = 0; nt < 4; ++nt)
#pragma unroll
    for (int r = 0; r < 4; ++r)
      o_buf[w][quad * 4 + r][nt * 16 + ln] = o_acc[nt][r];
#pragma unroll
  for (int r = 0; r < 4; ++r) l_buf[w][quad * 4 + r][ln] = l_part[r];
  __syncthreads();

#pragma unroll
  for (int rr = 0; rr < 2; ++rr) {
    const int row = w + rr * 8;
    float o = 0.f, lsum = 0.f;
#pragma unroll
    for (int ww = 0; ww < 8; ++ww) {
      o += o_buf[ww][row][lane];
      lsum += l_buf[ww][row][lane & 15];
    }
#pragma unroll
    for (int off = 1; off < 16; off <<= 1) lsum += __shfl_xor(lsum, off);
    out[(bt + qr0 + row) * HS_ + lane] = o / lsum;
  }
}

// ---------------------------------------------------------------------------
extern "C" void kernel_launch(void* const* d_in, const int* in_sizes, int n_in,
                              void* d_out, int out_size, void* d_ws,
                              size_t ws_size, hipStream_t stream) {
  (void)in_sizes; (void)n_in; (void)out_size; (void)ws_size;
  const float* xq = (const float*)d_in[0];   // fp32 in / fp32 out: proven R4
  const float* xkv = (const float*)d_in[1];
  const float* Wq = (const float*)d_in[2];
  const float* Wk = (const float*)d_in[3];
  const float* Wv = (const float*)d_in[4];
  float* out = (float*)d_out;

  char* ws = (char*)d_ws;
  bf16_t* q = (bf16_t*)ws;                              // 2 MB  [B*T][64]
  bf16_t* kk = (bf16_t*)(ws + (2u << 20));              // 2 MB  [B*T][64]
  bf16_t* vT = (bf16_t*)(ws + (4u << 20));              // 2 MB  [B][64][T]
  bf16_t* pq = (bf16_t*)(ws + (6u << 20));              // 128 KB packed W
  bf16_t* pk = (bf16_t*)(ws + (6u << 20) + (128u << 10));
  bf16_t* pv = (bf16_t*)(ws + (6u << 20) + (256u << 10));

  repack_w<<<dim3(32, 3), 256, 0, stream>>>(Wq, Wk, Wv, pq, pk, pv);
  proj_mfma<<<dim3(256, 2), 512, 0, stream>>>(xq, xkv, pq, pk, pv, q, kk, vT);
  attn_mfma<<<dim3(1024), 512, 0, stream>>>(q, kk, vT, out);
}

// Round 8
// 217.742 us; speedup vs baseline: 7.7539x; 1.0090x over previous
//
#include <hip/hip_runtime.h>

typedef __bf16 bf16_t;
typedef __bf16 bf16x8 __attribute__((ext_vector_type(8)));
typedef float f32x4 __attribute__((ext_vector_type(4)));
typedef unsigned short u16x4 __attribute__((ext_vector_type(4)));

#define B_ 8
#define T_ 2048
#define C_ 1024
#define HS_ 64
#define VSTRIDE 2080  // vT row stride (T_+32): de-alias 4KB channel hotspot

#define MFMA __builtin_amdgcn_mfma_f32_16x16x32_bf16

__device__ __forceinline__ float fast_exp2(float x) {
#if __has_builtin(__builtin_amdgcn_exp2f)
  return __builtin_amdgcn_exp2f(x);
#else
  return exp2f(x);
#endif
}

// async 16B/lane global->LDS: per-lane gsrc, wave-uniform LDS base (+lane*16)
__device__ __forceinline__ void async_ld16(const float* gsrc, float* lds_dst) {
  __builtin_amdgcn_global_load_lds(
      (const __attribute__((address_space(1))) void*)gsrc,
      (__attribute__((address_space(3))) void*)lds_dst, 16, 0, 0);
}

// ---------------------------------------------------------------------------
// Kernel 1: repack W [1024][64] fp32 -> bf16 MFMA B-fragment order.
// Pack index: ((kc*4 + nt)*64 + lane)*8 + j  =  W[kc*32 + quad*8 + j][nt*16 + ln]
// ---------------------------------------------------------------------------
__global__ __launch_bounds__(256) void repack_w(
    const float* __restrict__ Wq, const float* __restrict__ Wk,
    const float* __restrict__ Wv, bf16_t* __restrict__ pq,
    bf16_t* __restrict__ pk, bf16_t* __restrict__ pv) {
  const float* W = (blockIdx.y == 0) ? Wq : ((blockIdx.y == 1) ? Wk : Wv);
  bf16_t* P = (blockIdx.y == 0) ? pq : ((blockIdx.y == 1) ? pk : pv);
  int t = blockIdx.x * 256 + threadIdx.x;  // 0..8191
  int lane = t & 63, nt = (t >> 6) & 3, kc = t >> 8;
  int quad = lane >> 4, ln = lane & 15;
  bf16x8 v;
#pragma unroll
  for (int j = 0; j < 8; ++j)
    v[j] = (bf16_t)W[(kc * 32 + quad * 8 + j) * HS_ + nt * 16 + ln];
  *(bf16x8*)(P + (size_t)t * 8) = v;
}

// ---------------------------------------------------------------------------
// Kernel 2: MFMA projections with global_load_lds x-staging.
// R7 diagnosis: direct A-loads put lanes 4KB apart (16 discontiguous 64B
// segments/instr, L2-channel hotspot) -> BW stuck at ~1.3 TB/s HBM. Now each
// wave stages its 16 rows as CONTIGUOUS 1KB runs into LDS (async, deep
// queue, no VGPR round-trip), then reads A-frags from LDS (row stride 260
// dwords -> 2-way banks = free). Waves are fully independent: no barriers,
// just s_waitcnt vmcnt(0) between stage and compute. K-split removed.
// y=0: q = x_q@Wq; y=1: k = x_kv@Wk AND v = x_kv@Wv (shared A).
// q,k row-major [B*T][64] bf16; v transposed [B][64][VSTRIDE] bf16.
// ---------------------------------------------------------------------------
__global__ __launch_bounds__(256) void proj_mfma(
    const float* __restrict__ xq, const float* __restrict__ xkv,
    const bf16_t* __restrict__ pq, const bf16_t* __restrict__ pk,
    const bf16_t* __restrict__ pv, bf16_t* __restrict__ q,
    bf16_t* __restrict__ k, bf16_t* __restrict__ vT) {
  __shared__ float Xb[64][260];  // 65 KB; 256-col chunk, +4 dword row pad

  const int rt = blockIdx.x;
  const bool is_kv = (blockIdx.y != 0);
  const int w = threadIdx.x >> 6, lane = threadIdx.x & 63;
  const int quad = lane >> 4, ln = lane & 15;
  const int m0blk = rt * 64;
  const int m0 = m0blk + w * 16;
  const float* x = is_kv ? xkv : xq;
  const bf16_t* p0 = is_kv ? pk : pq;

  f32x4 acc0[4], acc1[4];
#pragma unroll
  for (int nt = 0; nt < 4; ++nt) {
    acc0[nt] = (f32x4){0.f, 0.f, 0.f, 0.f};
    acc1[nt] = (f32x4){0.f, 0.f, 0.f, 0.f};
  }

  for (int c = 0; c < 4; ++c) {
    // ---- stage this wave's 16 rows x 256 cols (1KB contiguous per row) ----
#pragma unroll
    for (int i = 0; i < 16; ++i) {
      const int row = w * 16 + i;
      async_ld16(x + (size_t)(m0blk + row) * C_ + c * 256 + lane * 4,
                 &Xb[row][0]);
    }
    asm volatile("s_waitcnt vmcnt(0)" ::: "memory");

    // ---- compute 8 kc sub-chunks from LDS ----
#pragma unroll 2
    for (int kc2 = 0; kc2 < 8; ++kc2) {
      const int kcg = c * 8 + kc2;
      f32x4 xlo = *(const f32x4*)&Xb[w * 16 + ln][kc2 * 32 + quad * 8];
      f32x4 xhi = *(const f32x4*)&Xb[w * 16 + ln][kc2 * 32 + quad * 8 + 4];
      bf16x8 a;
#pragma unroll
      for (int j = 0; j < 4; ++j) {
        a[j] = (bf16_t)xlo[j];
        a[4 + j] = (bf16_t)xhi[j];
      }
#pragma unroll
      for (int nt = 0; nt < 4; ++nt) {
        bf16x8 b = *(const bf16x8*)(p0 + ((size_t)(kcg * 4 + nt) * 64 + lane) * 8);
        acc0[nt] = MFMA(a, b, acc0[nt], 0, 0, 0);
      }
      if (is_kv) {
#pragma unroll
        for (int nt = 0; nt < 4; ++nt) {
          bf16x8 b = *(const bf16x8*)(pv + ((size_t)(kcg * 4 + nt) * 64 + lane) * 8);
          acc1[nt] = MFMA(a, b, acc1[nt], 0, 0, 0);
        }
      }
    }
    // same wave re-stages its own rows next chunk; ds ordering within wave
    asm volatile("" ::: "memory");
  }

  if (!is_kv) {
#pragma unroll
    for (int nt = 0; nt < 4; ++nt)
#pragma unroll
      for (int r = 0; r < 4; ++r)
        q[(size_t)(m0 + quad * 4 + r) * HS_ + nt * 16 + ln] = (bf16_t)acc0[nt][r];
  } else {
#pragma unroll
    for (int nt = 0; nt < 4; ++nt)
#pragma unroll
      for (int r = 0; r < 4; ++r)
        k[(size_t)(m0 + quad * 4 + r) * HS_ + nt * 16 + ln] = (bf16_t)acc0[nt][r];
    const int bb = m0 >> 11, t0 = m0 & (T_ - 1);
#pragma unroll
    for (int nt = 0; nt < 4; ++nt) {
      u16x4 pk4;
#pragma unroll
      for (int r = 0; r < 4; ++r) {
        bf16_t h = (bf16_t)acc1[nt][r];
        pk4[r] = *(unsigned short*)&h;
      }
      *(u16x4*)((unsigned short*)vT + ((size_t)(bb * HS_ + nt * 16 + ln)) * VSTRIDE +
                t0 + quad * 4) = pk4;
    }
  }
}

// ---------------------------------------------------------------------------
// Kernel 3: causal flash attention, KV-split x8, parallel epilogue.
// grid = B*128; block = one 16-row q-group, 8 waves; wave w: k-tiles
// {w, w+8, ...} <= td. Fixed softmax max (|s| <~ 1.5): p = exp2(s*scl),
// l deferred; partials combine by ADDITION through LDS; wave w reduces rows
// {w, w+8} (coalesced output stores). vT rows padded to VSTRIDE to spread
// L2 channels. P transpose stride 80 elems (16B-aligned for ds_read_b128).
// scale = C^-0.5 = 1/32 (reference uses d_model, not head_size).
// ---------------------------------------------------------------------------
__global__ __launch_bounds__(512) void attn_mfma(
    const bf16_t* __restrict__ q, const bf16_t* __restrict__ k,
    const bf16_t* __restrict__ vT, float* __restrict__ out) {
  __shared__ bf16_t p_lds[8][16][80];   // 20 KB: per-wave P transpose
  __shared__ float o_buf[8][16][66];    // 33 KB: all 8 waves' partial O
  __shared__ float l_buf[8][16][17];    //  8.7 KB: per-lane l partials

  const int b = blockIdx.x >> 7;
  const int gq = blockIdx.x & 127;      // 16-row q-group within batch
  const int w = threadIdx.x >> 6, lane = threadIdx.x & 63;
  const int quad = lane >> 4, ln = lane & 15;
  const int qr0 = gq * 16;
  const size_t bt = (size_t)b * T_;
  const int td = gq >> 2;               // diagonal 64-key tile index

  bf16x8 aq[2];
#pragma unroll
  for (int hc = 0; hc < 2; ++hc)
    aq[hc] = *(const bf16x8*)(q + (bt + qr0 + ln) * HS_ + hc * 32 + quad * 8);

  f32x4 o_acc[4];
  float l_part[4] = {0.f, 0.f, 0.f, 0.f};
#pragma unroll
  for (int nt = 0; nt < 4; ++nt) o_acc[nt] = (f32x4){0.f, 0.f, 0.f, 0.f};
  const float scl = 0.03125f * 1.44269504088896340736f;  // C^-0.5 * log2(e)

  for (int t = w; t <= td; t += 8) {
    const int kr0 = t * 64;

    // ---- S = Q K^T (16 q-rows x 64 keys) ----
    f32x4 s[4];
#pragma unroll
    for (int nt = 0; nt < 4; ++nt) s[nt] = (f32x4){0.f, 0.f, 0.f, 0.f};
#pragma unroll
    for (int hc = 0; hc < 2; ++hc)
#pragma unroll
      for (int nt = 0; nt < 4; ++nt) {
        bf16x8 bk = *(const bf16x8*)(k + (bt + kr0 + nt * 16 + ln) * HS_ +
                                     hc * 32 + quad * 8);
        s[nt] = MFMA(aq[hc], bk, s[nt], 0, 0, 0);
      }

    // ---- p = exp(s/32), mask diagonal tile, accumulate l, stage P ----
    const bool diag = (t == td);
#pragma unroll
    for (int nt = 0; nt < 4; ++nt)
#pragma unroll
      for (int r = 0; r < 4; ++r) {
        float e = fast_exp2(s[nt][r] * scl);
        if (diag && (kr0 + nt * 16 + ln > qr0 + quad * 4 + r)) e = 0.f;
        l_part[r] += e;
        p_lds[w][quad * 4 + r][nt * 16 + ln] = (bf16_t)e;
      }

    // ---- O += P V (per-wave LDS slice; same-wave DS ordering) ----
#pragma unroll
    for (int kc = 0; kc < 2; ++kc) {
      bf16x8 ap = *(const bf16x8*)&p_lds[w][ln][kc * 32 + quad * 8];
#pragma unroll
      for (int nt = 0; nt < 4; ++nt) {
        bf16x8 bv = *(const bf16x8*)(vT +
                                     ((size_t)(b * HS_ + nt * 16 + ln)) * VSTRIDE +
                                     kr0 + kc * 32 + quad * 8);
        o_acc[nt] = MFMA(ap, bv, o_acc[nt], 0, 0, 0);
      }
    }
  }

  // ---- all waves dump partials; combine split across waves ----
#pragma unroll
  for (int nt = 0; nt < 4; ++nt)
#pragma unroll
    for (int r = 0; r < 4; ++r)
      o_buf[w][quad * 4 + r][nt * 16 + ln] = o_acc[nt][r];
#pragma unroll
  for (int r = 0; r < 4; ++r) l_buf[w][quad * 4 + r][ln] = l_part[r];
  __syncthreads();

#pragma unroll
  for (int rr = 0; rr < 2; ++rr) {
    const int row = w + rr * 8;
    float o = 0.f, lsum = 0.f;
#pragma unroll
    for (int ww = 0; ww < 8; ++ww) {
      o += o_buf[ww][row][lane];
      lsum += l_buf[ww][row][lane & 15];
    }
#pragma unroll
    for (int off = 1; off < 16; off <<= 1) lsum += __shfl_xor(lsum, off);
    out[(bt + qr0 + row) * HS_ + lane] = o / lsum;
  }
}

// ---------------------------------------------------------------------------
extern "C" void kernel_launch(void* const* d_in, const int* in_sizes, int n_in,
                              void* d_out, int out_size, void* d_ws,
                              size_t ws_size, hipStream_t stream) {
  (void)in_sizes; (void)n_in; (void)out_size; (void)ws_size;
  const float* xq = (const float*)d_in[0];   // fp32 in / fp32 out: proven R4
  const float* xkv = (const float*)d_in[1];
  const float* Wq = (const float*)d_in[2];
  const float* Wk = (const float*)d_in[3];
  const float* Wv = (const float*)d_in[4];
  float* out = (float*)d_out;

  char* ws = (char*)d_ws;
  bf16_t* q = (bf16_t*)ws;                              // 2 MB   [B*T][64]
  bf16_t* kk = (bf16_t*)(ws + (2u << 20));              // 2 MB   [B*T][64]
  bf16_t* vT = (bf16_t*)(ws + (4u << 20));              // 2.04MB [B][64][VSTRIDE]
  bf16_t* pq = (bf16_t*)(ws + (6656u << 10));           // 128 KB packed W @6.5MB
  bf16_t* pk = (bf16_t*)(ws + (6784u << 10));
  bf16_t* pv = (bf16_t*)(ws + (6912u << 10));

  repack_w<<<dim3(32, 3), 256, 0, stream>>>(Wq, Wk, Wv, pq, pk, pv);
  proj_mfma<<<dim3(256, 2), 256, 0, stream>>>(xq, xkv, pq, pk, pv, q, kk, vT);
  attn_mfma<<<dim3(1024), 512, 0, stream>>>(q, kk, vT, out);
}